// Round 2
// baseline (467.511 us; speedup 1.0000x reference)
//
#include <hip/hip_runtime.h>

// Cost volume: volume[b,d,h,w] = mean_c left[b,c,h,w] * right[b,c,h,w-d], 0 for w<d.
// B=8 C=64 H=160 W=320 D=48, f32 in / f32 out.
//
// One block per (b,h) row. Channels streamed through LDS in 8 chunks of 8,
// double-buffered (40 KB LDS -> 4 blocks/CU). global_load_lds width-16 staging.
// Thread t owns one w-quad (wq = (t%80)*4, lanes contiguous -> 16B-stride
// conflict-free ds_read_b128) x one 16-deep d-tile (d0 = (t/80)*16).
// 240 active threads of 256.

constexpr int C_ = 64, H_ = 160, W_ = 320, D_ = 48;
constexpr int HW_ = H_ * W_;            // 51200
constexpr int CK_ = 8;                  // channels per LDS chunk
constexpr int CHF = CK_ * W_;           // 2560 floats per chunk buffer
// LDS floats: [L0: 0..2560) [L1: 2560..5120) [R0: 5120..7680) [R1: 7680..10240)
// R reads may underflow by up to 48 floats (w<d diagonal) -> land in L/R buffers
// (valid LDS, finite garbage) and only feed store-masked outputs.

typedef __attribute__((address_space(1))) unsigned int gu32;
typedef __attribute__((address_space(3))) unsigned int lu32;

__device__ __forceinline__ void gload_lds16(const float* g, float* l) {
  __builtin_amdgcn_global_load_lds((const gu32*)g, (lu32*)l, 16, 0, 0);
}

__global__ __launch_bounds__(256, 4)
void corvol_kernel(const float* __restrict__ L, const float* __restrict__ R,
                   float* __restrict__ out) {
  __shared__ __align__(16) float lds[4 * CHF];   // 40960 B

  const int tid  = threadIdx.x;
  const int lane = tid & 63;
  const int wv   = tid >> 6;

  const int bh = blockIdx.x;            // b*H + h
  const int b  = bh / H_;
  const int h  = bh - b * H_;
  const int inbase = b * (C_ * HW_) + h * W_;
  const float* Lbh = L + inbase;
  const float* Rbh = R + inbase;

  // thread -> (d-tile, w-quad): 80 quads x 3 d-tiles = 240 active threads
  const int q  = tid % 80;
  const int dt = tid / 80;
  const int wq = q * 4;
  const int d0 = dt * 16;
  const bool active = (dt < 3);

  float acc[16][4];
#pragma unroll
  for (int i = 0; i < 16; ++i)
#pragma unroll
    for (int j = 0; j < 4; ++j) acc[i][j] = 0.0f;

  auto stage = [&](int ck, int p) {
    const int c0 = ck * CK_;
    // 10 segments of 1024 B per matrix; wave wv does segs wv, wv+4, wv+8 (<10)
#pragma unroll
    for (int s = 0; s < 3; ++s) {
      const int seg = wv + s * 4;
      if (seg < 10) {
        const int f = seg * 256 + lane * 4;    // float index in [8][320] chunk
        const int c = f / W_;                  // lane 16B never straddles a row
        const int w = f - c * W_;
        const int goff = (c0 + c) * HW_ + w;
        gload_lds16(Lbh + goff, &lds[p * CHF + seg * 256]);
        gload_lds16(Rbh + goff, &lds[2 * CHF + p * CHF + seg * 256]);
      }
    }
  };

  auto compute = [&](int p) {
    const float* Lc = &lds[p * CHF];
    const float* Rc = &lds[2 * CHF + p * CHF];
#pragma unroll
    for (int c = 0; c < CK_; ++c) {
      const float4 a = *(const float4*)(Lc + c * W_ + wq);
      const float* rp = Rc + c * W_ + (wq - d0 - 16);  // 16B-aligned, may underflow
      float rv[20];
#pragma unroll
      for (int k = 0; k < 5; ++k) {
        const float4 r = *(const float4*)(rp + 4 * k);
        rv[4 * k + 0] = r.x; rv[4 * k + 1] = r.y;
        rv[4 * k + 2] = r.z; rv[4 * k + 3] = r.w;
      }
      const float la[4] = {a.x, a.y, a.z, a.w};
#pragma unroll
      for (int dd = 0; dd < 16; ++dd)
#pragma unroll
        for (int j = 0; j < 4; ++j)
          acc[dd][j] = fmaf(la[j], rv[16 + j - dd], acc[dd][j]);
    }
  };

  stage(0, 0);
  __syncthreads();

#pragma unroll 1
  for (int ck = 0; ck < 8; ++ck) {
    if (ck < 7) stage(ck + 1, (ck + 1) & 1);   // prefetch next chunk
    if (active) compute(ck & 1);
    __syncthreads();                            // drains vmcnt before buffer reuse
  }

  if (active) {
    constexpr float sc = 1.0f / 64.0f;
    const int ob = b * (D_ * HW_) + h * W_ + wq;
#pragma unroll
    for (int dd = 0; dd < 16; ++dd) {
      const int d = d0 + dd;
      float4 o;
      o.x = (wq + 0 >= d) ? acc[dd][0] * sc : 0.0f;
      o.y = (wq + 1 >= d) ? acc[dd][1] * sc : 0.0f;
      o.z = (wq + 2 >= d) ? acc[dd][2] * sc : 0.0f;
      o.w = (wq + 3 >= d) ? acc[dd][3] * sc : 0.0f;
      *(float4*)(out + ob + d * HW_) = o;
    }
  }
}

extern "C" void kernel_launch(void* const* d_in, const int* in_sizes, int n_in,
                              void* d_out, int out_size, void* d_ws, size_t ws_size,
                              hipStream_t stream) {
  const float* left  = (const float*)d_in[0];
  const float* right = (const float*)d_in[1];
  float* out = (float*)d_out;
  const int B = 8;
  dim3 grid(B * H_), block(256);
  corvol_kernel<<<grid, block, 0, stream>>>(left, right, out);
}

// Round 4
// 255.222 us; speedup vs baseline: 1.8318x; 1.8318x over previous
//
#include <hip/hip_runtime.h>

// Cost volume: volume[b,d,h,w] = mean_c left[b,c,h,w] * right[b,c,h,w-d], 0 for w<d.
// B=8 C=64 H=160 W=320 D=48, f32 in / f32 out.
//
// One block of 512 threads per (b,h) row. Channels streamed through LDS in
// 8 chunks of 8, double-buffered (40 KB). global_load_lds width-16 staging.
// Thread t owns one w-quad (wq = (t%80)*4; lanes contiguous -> 16B-stride
// conflict-free ds_read_b128) x one 8-deep d-tile (d0 = (t/80)*8).
// 480 active threads of 512. acc[8][4]=32 VGPRs -> no spill pressure.

constexpr int C_ = 64, H_ = 160, W_ = 320, D_ = 48;
constexpr int HW_ = H_ * W_;            // 51200
constexpr int CK_ = 8;                  // channels per LDS chunk
constexpr int CHF = CK_ * W_;           // 2560 floats per chunk buffer
// LDS floats: [L0: 0..2560) [L1: 2560..5120) [R0: 5120..7680) [R1: 7680..10240)
// R reads may underflow by up to 44 floats (w<d diagonal) -> land in preceding
// buffer (valid LDS, finite garbage) and only feed store-masked outputs.

typedef __attribute__((address_space(1))) unsigned int gu32;
typedef __attribute__((address_space(3))) unsigned int lu32;
typedef float f32x4 __attribute__((ext_vector_type(4)));

__device__ __forceinline__ void gload_lds16(const float* g, float* l) {
  __builtin_amdgcn_global_load_lds((const gu32*)g, (lu32*)l, 16, 0, 0);
}

__global__ __launch_bounds__(512, 2)
void corvol_kernel(const float* __restrict__ L, const float* __restrict__ R,
                   float* __restrict__ out) {
  __shared__ __align__(16) float lds[4 * CHF];   // 40960 B

  const int tid  = threadIdx.x;
  const int lane = tid & 63;
  const int wv   = tid >> 6;              // 0..7

  const int bh = blockIdx.x;              // b*H + h
  const int b  = bh / H_;
  const int h  = bh - b * H_;
  const int inbase = b * (C_ * HW_) + h * W_;
  const float* Lbh = L + inbase;
  const float* Rbh = R + inbase;

  // thread -> (d-tile, w-quad): 80 quads x 6 d-tiles = 480 active threads
  const int q  = tid % 80;
  const int dt = tid / 80;
  const int wq = q * 4;
  const int d0 = dt * 8;
  const bool active = (dt < 6);

  float acc[8][4];
#pragma unroll
  for (int i = 0; i < 8; ++i)
#pragma unroll
    for (int j = 0; j < 4; ++j) acc[i][j] = 0.0f;

  auto stage = [&](int ck, int p) {
    const int c0 = ck * CK_;
    // 10 segments of 1024 B per matrix; wave wv does segs wv, wv+8 (<10)
#pragma unroll
    for (int s = 0; s < 2; ++s) {
      const int seg = wv + s * 8;
      if (seg < 10) {
        const int f = seg * 256 + lane * 4;    // float index in [8][320] chunk
        const int c = f / W_;                  // lane 16B never straddles a row
        const int w = f - c * W_;
        const int goff = (c0 + c) * HW_ + w;
        gload_lds16(Lbh + goff, &lds[p * CHF + seg * 256]);
        gload_lds16(Rbh + goff, &lds[2 * CHF + p * CHF + seg * 256]);
      }
    }
  };

  auto compute = [&](int p) {
    const float* Lc = &lds[p * CHF];
    const float* Rc = &lds[2 * CHF + p * CHF];
#pragma unroll
    for (int c = 0; c < CK_; ++c) {
      const f32x4 a = *(const f32x4*)(Lc + c * W_ + wq);
      const float* rp = Rc + c * W_ + (wq - d0 - 8);  // 16B-aligned; may underflow
      float rv[12];
#pragma unroll
      for (int k = 0; k < 3; ++k) {
        const f32x4 r = *(const f32x4*)(rp + 4 * k);
        rv[4 * k + 0] = r.x; rv[4 * k + 1] = r.y;
        rv[4 * k + 2] = r.z; rv[4 * k + 3] = r.w;
      }
      const float la[4] = {a.x, a.y, a.z, a.w};
#pragma unroll
      for (int dd = 0; dd < 8; ++dd)
#pragma unroll
        for (int j = 0; j < 4; ++j)
          acc[dd][j] = fmaf(la[j], rv[8 + j - dd], acc[dd][j]);
    }
  };

  stage(0, 0);
  __syncthreads();

#pragma unroll 1
  for (int ck = 0; ck < 8; ++ck) {
    if (ck < 7) stage(ck + 1, (ck + 1) & 1);   // prefetch next chunk (in flight during compute)
    if (active) compute(ck & 1);
    __syncthreads();                            // drains vmcnt before buffer reuse
  }

  if (active) {
    constexpr float sc = 1.0f / 64.0f;
    const int ob = b * (D_ * HW_) + h * W_ + wq;
#pragma unroll
    for (int dd = 0; dd < 8; ++dd) {
      const int d = d0 + dd;
      f32x4 o;
      o.x = (wq + 0 >= d) ? acc[dd][0] * sc : 0.0f;
      o.y = (wq + 1 >= d) ? acc[dd][1] * sc : 0.0f;
      o.z = (wq + 2 >= d) ? acc[dd][2] * sc : 0.0f;
      o.w = (wq + 3 >= d) ? acc[dd][3] * sc : 0.0f;
      __builtin_nontemporal_store(o, (f32x4*)(out + ob + d * HW_));
    }
  }
}

extern "C" void kernel_launch(void* const* d_in, const int* in_sizes, int n_in,
                              void* d_out, int out_size, void* d_ws, size_t ws_size,
                              hipStream_t stream) {
  const float* left  = (const float*)d_in[0];
  const float* right = (const float*)d_in[1];
  float* out = (float*)d_out;
  const int B = 8;
  dim3 grid(B * H_), block(512);
  corvol_kernel<<<grid, block, 0, stream>>>(left, right, out);
}